// Round 6
// baseline (528.301 us; speedup 1.0000x reference)
//
#include <hip/hip_runtime.h>
#include <stdint.h>

#define BB   2
#define SS   2048
#define DD   1024
#define HH   16
#define DKK  64
#define MM   (BB*SS)   // 4096 rows total

typedef __attribute__((ext_vector_type(4))) float f32x4;
typedef __attribute__((ext_vector_type(8))) short s16x8;

#define MFMA_B16(a, b, c) __builtin_amdgcn_mfma_f32_16x16x32_bf16((a), (b), (c), 0, 0, 0)

__device__ __forceinline__ ushort f2bf(float f) {
  uint u = __float_as_uint(f);
  u += 0x7FFFu + ((u >> 16) & 1u);   // round-to-nearest-even
  return (ushort)(u >> 16);
}
__device__ __forceinline__ float bf2f(ushort u) {
  return __uint_as_float((uint)u << 16);
}

// ---------------- fp32 -> bf16 convert (8 elems/thread) ----------------
__global__ void cvt_kernel(const float* __restrict__ src, ushort* __restrict__ dst, int n) {
  int i = (blockIdx.x * 256 + threadIdx.x) * 8;
  if (i >= n) return;
  const float4* s4 = (const float4*)(src + i);
  float4 a = s4[0], b = s4[1];
  union { ushort u[8]; s16x8 v; } r;
  r.u[0] = f2bf(a.x); r.u[1] = f2bf(a.y); r.u[2] = f2bf(a.z); r.u[3] = f2bf(a.w);
  r.u[4] = f2bf(b.x); r.u[5] = f2bf(b.y); r.u[6] = f2bf(b.z); r.u[7] = f2bf(b.w);
  *(s16x8*)(dst + i) = r.v;
}

// ---------------- Y = A @ W^T  (A:[4096,1024] bf16, W:[1024,1024] bf16) ----------------
// mode 0: Q-proj -> [B,H,S,DK] bf16, scaled by 1/8
// mode 1: K-proj -> [B,H,S,DK] bf16
// mode 2: V-proj -> [B,H,DK,S] bf16 (transposed)
// mode 3: O-proj -> [4096,1024] fp32 (d_out)
__global__ __launch_bounds__(256, 2) void proj_gemm(
    const ushort* __restrict__ A, const ushort* __restrict__ W,
    void* __restrict__ outp, int mode)
{
  __shared__ ushort As[128 * 32];
  __shared__ ushort Bs[128 * 32];
  const int tid  = threadIdx.x;
  const int lane = tid & 63, wave = tid >> 6;
  const int q = lane & 15, g = lane >> 4;
  const int wr = wave >> 1, wc = wave & 1;
  const int mblk = blockIdx.x * 128, nblk = blockIdx.y * 128;

  f32x4 acc[4][4];
  {
    f32x4 z = {0.f, 0.f, 0.f, 0.f};
#pragma unroll
    for (int i = 0; i < 4; ++i)
#pragma unroll
      for (int j = 0; j < 4; ++j) acc[i][j] = z;
  }

  const int r0 = tid >> 2;            // staging row
  const int e0 = (tid & 3) * 8;       // staging element offset within row
  for (int k0 = 0; k0 < 1024; k0 += 32) {
#pragma unroll
    for (int it = 0; it < 2; ++it) {
      const int row = r0 + it * 64;
      *(s16x8*)&As[row * 32 + e0] = *(const s16x8*)(A + (size_t)(mblk + row) * 1024 + k0 + e0);
      *(s16x8*)&Bs[row * 32 + e0] = *(const s16x8*)(W + (size_t)(nblk + row) * 1024 + k0 + e0);
    }
    __syncthreads();
    s16x8 af[4], bf[4];
#pragma unroll
    for (int t = 0; t < 4; ++t) {
      af[t] = *(const s16x8*)&As[(wr * 64 + t * 16 + q) * 32 + g * 8];
      bf[t] = *(const s16x8*)&Bs[(wc * 64 + t * 16 + q) * 32 + g * 8];
    }
#pragma unroll
    for (int mt = 0; mt < 4; ++mt)
#pragma unroll
      for (int nt = 0; nt < 4; ++nt)
        acc[mt][nt] = MFMA_B16(af[mt], bf[nt], acc[mt][nt]);
    __syncthreads();
  }

  // epilogue: C layout col = lane&15 (N), row = (lane>>4)*4 + j (M)
  if (mode == 3) {
    float* O = (float*)outp;
#pragma unroll
    for (int mt = 0; mt < 4; ++mt)
#pragma unroll
      for (int nt = 0; nt < 4; ++nt)
#pragma unroll
        for (int j = 0; j < 4; ++j) {
          const int s = mblk + wr * 64 + mt * 16 + g * 4 + j;
          const int o = nblk + wc * 64 + nt * 16 + q;
          O[(size_t)s * DD + o] = acc[mt][nt][j];
        }
  } else if (mode == 2) {
    ushort* Vt = (ushort*)outp;
#pragma unroll
    for (int mt = 0; mt < 4; ++mt)
#pragma unroll
      for (int nt = 0; nt < 4; ++nt) {
        const int s0 = mblk + wr * 64 + mt * 16 + g * 4;
        const int o  = nblk + wc * 64 + nt * 16 + q;
        const int h = o >> 6, dk = o & 63;
        const int b = s0 >> 11, sr = s0 & 2047;
        ushort4 pk;
        pk.x = f2bf(acc[mt][nt][0]); pk.y = f2bf(acc[mt][nt][1]);
        pk.z = f2bf(acc[mt][nt][2]); pk.w = f2bf(acc[mt][nt][3]);
        *(ushort4*)(Vt + ((size_t)((b * 16 + h) * 64 + dk)) * SS + sr) = pk;
      }
  } else {
    // Q/K proj: LDS-staged epilogue -> full-row contiguous 16B/lane stores.
    const float scale = (mode == 0) ? 0.125f : 1.0f;
    ushort* P = (ushort*)outp;
    ushort* wl = As + wave * 1024;   // 2KB wave-private staging (reuse As)
    const int h0 = (nblk + wc * 64) >> 6;
#pragma unroll
    for (int mt = 0; mt < 4; ++mt) {
      const int s0 = mblk + wr * 64 + mt * 16;
      const int b  = s0 >> 11, sr0 = s0 & 2047;
#pragma unroll
      for (int nt = 0; nt < 4; ++nt)
#pragma unroll
        for (int j = 0; j < 4; ++j)
          wl[(g * 4 + j) * 64 + nt * 16 + q] = f2bf(acc[mt][nt][j] * scale);
      // same-wave LDS write->read: compiler inserts lgkmcnt wait
#pragma unroll
      for (int it = 0; it < 2; ++it) {
        s16x8 v = *(const s16x8*)((char*)wl + it * 1024 + lane * 16);
        const int lr = it * 8 + (lane >> 3);
        const int c  = (lane & 7) * 8;
        *(s16x8*)(P + ((size_t)((b * 16 + h0) * SS) + sr0 + lr) * DKK + c) = v;
      }
    }
  }
}

// ---------------- pass 1: rden[b][q][k] = 1/sum_h exp(s[b,h,q,k]) ----------------
// grid (8 kg, 128 qb, 2 b), 256 thr = 4 waves.  Block stages Q[16h][16q][64]
// (padded rows, 36 KB) once; each wave owns 4 of the block's 16 key-tiles and
// loops all 16 heads per tile, accumulating den in registers.  One wave owns
// each (q,k) tile across ALL heads -> no cross-wave exchange, no loop barriers.
// Same swapped-MFMA fragment math as the verified attention kernel:
// c[r] = s[key=krow+g*4+r][query=qrow+q].
__global__ __launch_bounds__(256, 2) void den_kernel(
    const ushort* __restrict__ Qp, const ushort* __restrict__ Kp,
    ushort* __restrict__ Rden)
{
  __shared__ ushort Qs[16 * 16 * 72];   // [h][q][72 padded] = 36 KB
  const int tid  = threadIdx.x;
  const int lane = tid & 63, w = tid >> 6;
  const int q = lane & 15, g = lane >> 4;
  const int kg = blockIdx.x, qb = blockIdx.y, b = blockIdx.z;
  const int qrow = qb * 16;

  // stage Q tile: thread t copies row (h = t>>4, qq = t&15)
  {
    const int h = tid >> 4, qq = tid & 15;
    const ushort* src = Qp + ((size_t)(b * 16 + h) * SS + qrow + qq) * DKK;
    ushort* dst = Qs + (h * 16 + qq) * 72;
#pragma unroll
    for (int j = 0; j < 8; ++j)
      *(s16x8*)(dst + j * 8) = *(const s16x8*)(src + j * 8);
  }
  __syncthreads();

  const ushort* Kbase = Kp + (size_t)(b * 16) * SS * DKK;
#pragma unroll
  for (int j4 = 0; j4 < 4; ++j4) {
    const int krow = (kg * 16 + w * 4 + j4) * 16;
    f32x4 den = {0.f, 0.f, 0.f, 0.f};
#pragma unroll 4
    for (int h = 0; h < 16; ++h) {
      const ushort* Kb = Kbase + (size_t)h * SS * DKK + (size_t)(krow + q) * DKK + g * 8;
      s16x8 kf0 = *(const s16x8*)(Kb);
      s16x8 kf1 = *(const s16x8*)(Kb + 32);
      const ushort* Qr = Qs + (h * 16 + q) * 72 + g * 8;
      s16x8 qf0 = *(const s16x8*)(Qr);
      s16x8 qf1 = *(const s16x8*)(Qr + 32);
      f32x4 c = {0.f, 0.f, 0.f, 0.f};
      c = MFMA_B16(kf0, qf0, c);
      c = MFMA_B16(kf1, qf1, c);
#pragma unroll
      for (int r = 0; r < 4; ++r) den[r] += __expf(c[r]);
    }
    ushort4 pk;
    pk.x = f2bf(1.0f / den[0]); pk.y = f2bf(1.0f / den[1]);
    pk.z = f2bf(1.0f / den[2]); pk.w = f2bf(1.0f / den[3]);
    *(ushort4*)(Rden + (size_t)b * SS * SS + (size_t)(qrow + q) * SS + krow + g * 4) = pk;
  }
}

// ---------------- pass 2: per-head attention, barrier-free ----------------
// grid 1024 x 256 thr = 4096 independent waves.  bid&31 = bh (b = bh&1,
// h = bh>>1) -> bid%8 pins 4 (b,h) pairs (2 MB K/V) per XCD L2.  Wave owns
// (b, h, 16-q tile), sweeps 2048 keys in 64 32-key phases: swapped-MFMA
// scores, attn = exp(s)*rden (rden loaded f32x4-shaped, matching pass-1
// layout), bf16 re-layout through wave-private LDS, K=32 PV.  No barriers
// in the loop; latency hidden by TLP.
__global__ __launch_bounds__(256, 2) void attn2_kernel(
    const ushort* __restrict__ Qp, const ushort* __restrict__ Kp,
    const ushort* __restrict__ Vt, const ushort* __restrict__ Rden,
    ushort* __restrict__ Ctx)
{
  __shared__ ushort aw_all[4][1024];   // 2 KB per wave

  const int tid  = threadIdx.x;
  const int lane = tid & 63;
  const int w    = tid >> 6;
  const int q    = lane & 15;
  const int g    = lane >> 4;
  const int bid  = blockIdx.x;
  const int bh   = bid & 31;
  const int b    = bh & 1, h = bh >> 1;
  const int qt   = (bid >> 5) * 4 + w;   // 0..127
  const int qrow = qt * 16;

  // Q fragments (B-operand: col=lane&15 -> q-row, dk contiguous per g)
  const ushort* Qb = Qp + ((size_t)(b * 16 + h) * SS + qrow + q) * DKK + g * 8;
  s16x8 qf0 = *(const s16x8*)(Qb);
  s16x8 qf1 = *(const s16x8*)(Qb + 32);

  const ushort* K0 = Kp + ((size_t)(b * 16 + h) * SS + q) * DKK + g * 8;
  const ushort* V0 = Vt + ((size_t)(b * 16 + h) * DKK + q) * SS + g * 8;
  const ushort* R0 = Rden + (size_t)b * SS * SS + (size_t)(qrow + q) * SS;

  f32x4 acc[4];
  {
    f32x4 z = {0.f, 0.f, 0.f, 0.f};
#pragma unroll
    for (int n = 0; n < 4; ++n) acc[n] = z;
  }

  char* aw = (char*)aw_all[w];
  const int swz = (q & 3) << 4;

  for (int kt = 0; kt < 64; ++kt) {
    const int base = kt * 32;
    // K fragments for both 16-key subtiles + rden (issued up front)
    const ushort* KbA = K0 + (size_t)base * DKK;
    const ushort* KbB = K0 + (size_t)(base + 16) * DKK;
    s16x8 kA0 = *(const s16x8*)(KbA);
    s16x8 kA1 = *(const s16x8*)(KbA + 32);
    s16x8 kB0 = *(const s16x8*)(KbB);
    s16x8 kB1 = *(const s16x8*)(KbB + 32);
    ushort4 rdA = *(const ushort4*)(R0 + base + g * 4);
    ushort4 rdB = *(const ushort4*)(R0 + base + 16 + g * 4);
    // scores (swapped: c[r] = s[key=base(+16)+g*4+r][query=qrow+q])
    f32x4 cA = {0.f, 0.f, 0.f, 0.f}, cB = {0.f, 0.f, 0.f, 0.f};
    cA = MFMA_B16(kA0, qf0, cA);
    cA = MFMA_B16(kA1, qf1, cA);
    cB = MFMA_B16(kB0, qf0, cB);
    cB = MFMA_B16(kB1, qf1, cB);
    // attn = exp(s) * rden
    float aA[4], aB[4];
#pragma unroll
    for (int r = 0; r < 4; ++r) {
      aA[r] = __expf(cA[r]) * bf2f(rdA.x * 0 + ((const ushort*)&rdA)[r]);
      aB[r] = __expf(cB[r]) * bf2f(((const ushort*)&rdB)[r]);
    }
    // bf16 re-layout via wave-private LDS (swizzled within 64B q-row)
    uint2 pA, pB;
    pA.x = (uint)f2bf(aA[0]) | ((uint)f2bf(aA[1]) << 16);
    pA.y = (uint)f2bf(aA[2]) | ((uint)f2bf(aA[3]) << 16);
    pB.x = (uint)f2bf(aB[0]) | ((uint)f2bf(aB[1]) << 16);
    pB.y = (uint)f2bf(aB[2]) | ((uint)f2bf(aB[3]) << 16);
    const int rowoff = q * 64;
    *(uint2*)(aw + rowoff + ((g * 8) ^ swz))      = pA;
    *(uint2*)(aw + rowoff + ((32 + g * 8) ^ swz)) = pB;
    // PV: A = attn row q (keys g*8..g*8+7 per lane), B = V^T rows
    s16x8 pa = *(const s16x8*)(aw + rowoff + ((g * 16) ^ swz));
#pragma unroll
    for (int n = 0; n < 4; ++n)
      acc[n] = MFMA_B16(pa, *(const s16x8*)(V0 + (size_t)(n * 16) * SS + base), acc[n]);
  }

  // epilogue: stage 16 rows x 64 cols (one head) in LDS, then coalesced
  // 16B/lane stores (each instr: 8 rows x 128B contiguous).
  ushort* aw16 = (ushort*)aw;
#pragma unroll
  for (int n = 0; n < 4; ++n)
#pragma unroll
    for (int j = 0; j < 4; ++j)
      aw16[(g * 4 + j) * 64 + n * 16 + q] = f2bf(acc[n][j]);
  ushort* P = Ctx + ((size_t)(b * SS) + qrow) * DD + h * 64;
#pragma unroll
  for (int it = 0; it < 2; ++it) {
    s16x8 v = *(const s16x8*)(aw + it * 1024 + lane * 16);
    const int lr = it * 8 + (lane >> 3);
    const int c  = (lane & 7) * 8;
    *(s16x8*)(P + (size_t)lr * DD + c) = v;
  }
}

extern "C" void kernel_launch(void* const* d_in, const int* in_sizes, int n_in,
                              void* d_out, int out_size, void* d_ws, size_t ws_size,
                              hipStream_t stream) {
  const float* Query = (const float*)d_in[0];
  const float* Key   = (const float*)d_in[1];
  const float* Value = (const float*)d_in[2];
  const float* Wq    = (const float*)d_in[3];
  const float* Wk    = (const float*)d_in[4];
  const float* Wv    = (const float*)d_in[5];
  const float* Wo    = (const float*)d_in[6];

  size_t off = 0;
  char* ws = (char*)d_ws;
  auto alloc = [&](size_t bytes) -> void* {
    void* p = ws + off;
    off += (bytes + 255) & ~(size_t)255;
    return p;
  };
  const size_t nX = (size_t)MM * DD;   // 4194304
  const size_t nW = (size_t)DD * DD;   // 1048576
  const size_t nS = (size_t)BB * SS * SS;  // 8388608
  ushort* Xq  = (ushort*)alloc(nX * 2);
  ushort* Xk  = (ushort*)alloc(nX * 2);
  ushort* Xv  = (ushort*)alloc(nX * 2);
  ushort* Wqb = (ushort*)alloc(nW * 2);
  ushort* Wkb = (ushort*)alloc(nW * 2);
  ushort* Wvb = (ushort*)alloc(nW * 2);
  ushort* Wob = (ushort*)alloc(nW * 2);
  ushort* Qp  = (ushort*)alloc(nX * 2);
  ushort* Kp  = (ushort*)alloc(nX * 2);
  ushort* Vtb = (ushort*)alloc(nX * 2);
  ushort* Rden = (ushort*)alloc(nS * 2);   // bf16 1/den, 16.7 MB
  ushort* Ctx = (ushort*)alloc(nX * 2);

  cvt_kernel<<<(int)(nX / 2048), 256, 0, stream>>>(Query, Xq, (int)nX);
  cvt_kernel<<<(int)(nX / 2048), 256, 0, stream>>>(Key,   Xk, (int)nX);
  cvt_kernel<<<(int)(nX / 2048), 256, 0, stream>>>(Value, Xv, (int)nX);
  cvt_kernel<<<(int)(nW / 2048), 256, 0, stream>>>(Wq, Wqb, (int)nW);
  cvt_kernel<<<(int)(nW / 2048), 256, 0, stream>>>(Wk, Wkb, (int)nW);
  cvt_kernel<<<(int)(nW / 2048), 256, 0, stream>>>(Wv, Wvb, (int)nW);
  cvt_kernel<<<(int)(nW / 2048), 256, 0, stream>>>(Wo, Wob, (int)nW);

  dim3 pg(32, 8), pb(256);
  proj_gemm<<<pg, pb, 0, stream>>>(Xq, Wqb, Qp, 0);
  proj_gemm<<<pg, pb, 0, stream>>>(Xk, Wkb, Kp, 1);
  proj_gemm<<<pg, pb, 0, stream>>>(Xv, Wvb, Vtb, 2);

  den_kernel<<<dim3(8, 128, 2), 256, 0, stream>>>(Qp, Kp, Rden);
  attn2_kernel<<<1024, 256, 0, stream>>>(Qp, Kp, Vtb, Rden, Ctx);

  proj_gemm<<<pg, pb, 0, stream>>>(Ctx, Wob, d_out, 3);
}